// Round 20
// baseline (89.540 us; speedup 1.0000x reference)
//
#include <hip/hip_runtime.h>

#define IMG 512
#define TW 64
#define TH 32
#define PROWS 42   // HNX row r = image row ty0-5+r
#define GST 64     // plane stride (elements)
#define RST 72     // RAW stride; rows r=4..38, col c at idx c+4
#define NTILE 4    // tiles per persistent block; grid = 4096/NTILE = 1024 = 4/CU

typedef __fp16 h2v __attribute__((ext_vector_type(2)));
union UH { unsigned u; h2v h; };
union US { unsigned short s; __fp16 h; };

__device__ __forceinline__ float nan0(float v){ return v==v ? v : 0.0f; }
__device__ __forceinline__ float min3f(float a,float b,float c){ return fminf(fminf(a,b),c); }
__device__ __forceinline__ float max3f(float a,float b,float c){ return fmaxf(fmaxf(a,b),c); }

__global__ __launch_bounds__(512, 8)
void simplenet_fused(const float* __restrict__ X,
                     const float* __restrict__ w0, const float* __restrict__ b0,
                     const float* __restrict__ w1, const float* __restrict__ w2,
                     const float* __restrict__ w3, const float* __restrict__ w4,
                     const float* __restrict__ w5, const float* __restrict__ w6,
                     float* __restrict__ out)
{
    // Persistent block: NTILE tiles, same by/bz (consecutive bx) -> L2 halo reuse.
    // Pipeline: after tile i's producer-compute, x0 regs are dead; reload them
    // with tile i+1's loads BEFORE tile i's consume -> latency hides under it.
    __shared__ unsigned       HNX[PROWS*GST];  // 10752 B packed f16 (min,-max)
    __shared__ unsigned short GHH[38*GST];     //  4864 B f16 gaussH
    __shared__ float          RAW[35*RST];     // 10080 B raw cols for trio

    const int tid = threadIdx.x;
    const int xo = tid & 63, ty = tid >> 6, y0 = ty*4;
    const float qn = __builtin_nanf("");

    const float W0c0=w0[0], W0c1=w0[1], B0=b0[0], B1=b0[1];
    const float W1c0=w1[0], W1c1=w1[1], W2c0=w2[0], W2c1=w2[1];
    const float W3c0=w3[0], W3c1=w3[1], W4c0=w4[0], W4c1=w4[1];
    const float W5c0=w5[0], W5c1=w5[1], W6c0=w6[0], W6c1=w6[1];
    const float G0=0.10628875f, G1=0.14032194f, G2=0.16577342f, G3=0.17523179f;

    auto load_task = [&](int t, const float* Xb, int tx0, int ty0, float* x) -> bool {
        const int r = t >> 4, g = t & 15;
        const int gy  = ty0 - 5 + r;
        const int gx0 = tx0 - 8 + 4*g;
        if ((unsigned)gy >= IMG) return true;
        const bool xs = (unsigned)gx0 > (unsigned)(IMG-20);
        if (!xs) {
#pragma unroll
            for (int j=0;j<5;++j) {
                const float4 q = *(const float4*)(Xb + gy*IMG + gx0 + 4*j);
                x[4*j]=q.x; x[4*j+1]=q.y; x[4*j+2]=q.z; x[4*j+3]=q.w;
            }
        } else {
            const float* row = Xb + gy*IMG;
#pragma unroll
            for (int i=0;i<20;++i) {
                const int gx = gx0 + i;
                const float v = row[min(max(gx,0),IMG-1)];
                x[i] = ((unsigned)gx < IMG) ? v : qn;
            }
        }
        return false;
    };
    auto compute_task = [&](int t, const float* x, bool oob, int tx0) {
        const int r = t >> 4, g = t & 15;
        const int wb = r*GST + 4*g;
        const bool rawrow = (r >= 4 && r <= 38);
        if (oob) {
            *(uint4*)&HNX[wb] = make_uint4(0x7BFF7BFFu,0x7BFF7BFFu,0x7BFF7BFFu,0x7BFF7BFFu);
            if (r >= 2 && r < 40)
                *(uint2*)&GHH[(r-2)*GST+4*g] = make_uint2(0u,0u);
            if (rawrow) {
                *(float4*)&RAW[(r-4)*RST + 4*g + 4] = make_float4(qn,qn,qn,qn);
                if (g==0)  RAW[(r-4)*RST + 3]  = qn;
                if (g==15) RAW[(r-4)*RST + 68] = qn;
            }
            return;
        }
        if (rawrow) {
            *(float4*)&RAW[(r-4)*RST + 4*g + 4] = make_float4(x[8],x[9],x[10],x[11]);
            if (g==0)  RAW[(r-4)*RST + 3]  = x[7];
            if (g==15) RAW[(r-4)*RST + 68] = x[12];
        }
        float mn[12], mx[12];
#pragma unroll
        for (int i=0;i<12;++i) {
            mn[i] = min3f(x[i+3],x[i+4],x[i+5]);
            mx[i] = max3f(x[i+3],x[i+4],x[i+5]);
        }
        unsigned hw[4];
#pragma unroll
        for (int k=0;k<4;++k) {             // 11-window = m3 at offsets 0,3,6,8
            const float hn = fminf(fminf(mn[k],mn[k+3]), fminf(mn[k+6],mn[k+8]));
            const float hx = fmaxf(fmaxf(mx[k],mx[k+3]), fmaxf(mx[k+6],mx[k+8]));
            UH c; c.h = __builtin_amdgcn_cvt_pkrtz(hn, -hx);
            hw[k] = c.u;
        }
        *(uint4*)&HNX[wb] = make_uint4(hw[0],hw[1],hw[2],hw[3]);
        if (r >= 2 && r < 40) {
            const bool xs = (unsigned)(tx0 - 8 + 4*g) > (unsigned)(IMG-20);
            float zz[10];
#pragma unroll
            for (int j=0;j<10;++j) zz[j] = xs ? nan0(x[5+j]) : x[5+j];
            float gh[4];
#pragma unroll
            for (int k=0;k<4;++k)
                gh[k] = G0*(zz[k]+zz[k+6]) + G1*(zz[k+1]+zz[k+5]) + G2*(zz[k+2]+zz[k+4]) + G3*zz[k+3];
            UH c01, c23;
            c01.h = __builtin_amdgcn_cvt_pkrtz(gh[0], gh[1]);
            c23.h = __builtin_amdgcn_cvt_pkrtz(gh[2], gh[3]);
            *(uint2*)&GHH[(r-2)*GST+4*g] = make_uint2(c01.u, c23.u);
        }
    };

    const bool has1 = tid < (PROWS*16 - 512);   // 160 threads own a 2nd task

    // tile decode: t -> (bx,by,bz); NTILE consecutive t share by,bz
    int tx0, ty0, bz; bool xe, ye; const float* Xb;
    auto decode = [&](int t) {
        const int bx = t & 7, by = (t >> 3) & 15;
        bz = t >> 7;
        tx0 = bx*TW; ty0 = by*TH;
        xe = (bx==0)||(bx==7); ye = (by==0)||(by==15);
        Xb = X + (size_t)bz*(IMG*IMG);
    };

    const int t0 = blockIdx.x * NTILE;
    decode(t0);
    float x0[20];
    bool oob0 = load_task(tid, Xb, tx0, ty0, x0);

    for (int i = 0; i < NTILE; ++i) {
        // ---- producer for current tile (x0 pre-loaded) ----
        float x1[20]; bool oob1 = true;
        if (has1) oob1 = load_task(512 + tid, Xb, tx0, ty0, x1);
        compute_task(tid, x0, oob0, tx0);
        if (has1) compute_task(512 + tid, x1, oob1, tx0);

        // save current-tile params for consume/store
        const int stx0 = tx0, sty0 = ty0, sbz = bz;
        const bool sxe = xe, sye = ye;

        __syncthreads();

        // ---- prefetch next tile's x0 (regs dead; latency hides under consume) ----
        if (i + 1 < NTILE) {
            decode(t0 + i + 1);
            oob0 = load_task(tid, Xb, tx0, ty0, x0);
        }

        // ---- consume: everything from LDS ----
        float a0[4], a1[4];
        {
            float L[6], C[6], R[6];
#pragma unroll
            for (int k=0;k<6;++k) {
                const int base = (y0+k)*RST + xo + 4;
                L[k]=RAW[base-1]; C[k]=RAW[base]; R[k]=RAW[base+1];
            }
            h2v q[14];
#pragma unroll
            for (int k=0;k<14;++k) { UH u; u.u = HNX[(y0+k)*GST+xo]; q[k] = u.h; }
            float wv[10];
#pragma unroll
            for (int k=0;k<10;++k) { US u; u.s = GHH[(y0+k)*GST+xo]; wv[k] = (float)u.h; }

            float hm[6], hx6[6];
#pragma unroll
            for (int k=0;k<6;++k) { hm[k]=min3f(L[k],C[k],R[k]); hx6[k]=max3f(L[k],C[k],R[k]); }
            float Lz[6], Rz[6];
#pragma unroll
            for (int k=0;k<6;++k) { Lz[k] = sxe ? nan0(L[k]) : L[k];
                                    Rz[k] = sxe ? nan0(R[k]) : R[k]; }
            const float Cz0 = sye ? nan0(C[0]) : C[0];
            const float Cz5 = sye ? nan0(C[5]) : C[5];
            const float up[4]={Cz0,C[1],C[2],C[3]};
            const float dn[4]={C[2],C[3],C[4],Cz5};
#pragma unroll
            for (int p=0;p<4;++p) {
                const float cr = 0.25f*(up[p] + dn[p] + Lz[p+1] + Rz[p+1]);
                a0[p] = B0 + W0c0*C[p+1] + W1c0*cr;
                a1[p] = B1 + W0c1*C[p+1] + W1c1*cr;
                const float mnv = min3f(hm[p],hm[p+1],hm[p+2]);
                const float mxv = max3f(hx6[p],hx6[p+1],hx6[p+2]);
                a0[p] += W3c0*mnv + W5c0*mxv;
                a1[p] += W3c1*mnv + W5c1*mxv;
            }
#pragma unroll
            for (int p=0;p<4;++p) {
                const float s = G0*(wv[p]+wv[p+6]) + G1*(wv[p+1]+wv[p+5])
                              + G2*(wv[p+2]+wv[p+4]) + G3*wv[p+3];
                a0[p] += W2c0*s; a1[p] += W2c1*s;
            }
            h2v s = q[10];
#pragma unroll
            for (int k=9;k>=4;--k) s = __builtin_elementwise_min(s, q[k]);
            const h2v S3 = __builtin_elementwise_min(s,  q[3]);
            const h2v S2 = __builtin_elementwise_min(S3, q[2]);
            const h2v S1 = __builtin_elementwise_min(S2, q[1]);
            const h2v S0 = __builtin_elementwise_min(S1, q[0]);
            const h2v p1 = q[11];
            const h2v p2 = __builtin_elementwise_min(p1, q[12]);
            const h2v p3 = __builtin_elementwise_min(p2, q[13]);
            const h2v o0 = S0;
            const h2v o1 = __builtin_elementwise_min(S1, p1);
            const h2v o2 = __builtin_elementwise_min(S2, p2);
            const h2v o3 = __builtin_elementwise_min(S3, p3);
            const float on[4] = {(float)o0[0], (float)o1[0], (float)o2[0], (float)o3[0]};
            const float ox[4] = {-(float)o0[1], -(float)o1[1], -(float)o2[1], -(float)o3[1]};
#pragma unroll
            for (int p=0;p<4;++p) {
                a0[p] += W4c0*on[p] + W6c0*ox[p];
                a1[p] += W4c1*on[p] + W6c1*ox[p];
            }
        }

        float* o0p = out + ((size_t)sbz*2 + 0)*(IMG*IMG) + (size_t)(sty0+y0)*IMG + stx0 + xo;
        float* o1p = o0p + (IMG*IMG);
#pragma unroll
        for (int p=0;p<4;++p) {
            o0p[(size_t)p*IMG] = a0[p];
            o1p[(size_t)p*IMG] = a1[p];
        }

        __syncthreads();   // LDS reuse safety before next tile's producer
    }
}

extern "C" void kernel_launch(void* const* d_in, const int* in_sizes, int n_in,
                              void* d_out, int out_size, void* d_ws, size_t ws_size,
                              hipStream_t stream) {
    const float* X  = (const float*)d_in[0];
    const float* w0 = (const float*)d_in[1];
    const float* b0 = (const float*)d_in[2];
    const float* w1 = (const float*)d_in[3];
    const float* w2 = (const float*)d_in[4];
    const float* w3 = (const float*)d_in[5];
    const float* w4 = (const float*)d_in[6];
    const float* w5 = (const float*)d_in[7];
    const float* w6 = (const float*)d_in[8];
    float* out = (float*)d_out;

    const int ntiles = (IMG/TW) * (IMG/TH) * 32;   // 4096
    simplenet_fused<<<ntiles / NTILE, 512, 0, stream>>>(X, w0, b0, w1, w2, w3, w4, w5, w6, out);
}

// Round 21
// 36.612 us; speedup vs baseline: 2.4456x; 2.4456x over previous
//
#include <hip/hip_runtime.h>

#define IMG 512
#define TW 64
#define TH 32
#define PROWS 42   // KNX row r = image row ty0-5+r
#define GST 64     // KNX stride (uint2 elements)
#define RST 72     // RAW stride; rows r=4..38 (image ty0-1..ty0+33), col c at idx c+4

typedef __fp16 h2v __attribute__((ext_vector_type(2)));
union UH { unsigned u; h2v h; };

__device__ __forceinline__ float nan0(float v){ return v==v ? v : 0.0f; }
__device__ __forceinline__ float min3f(float a,float b,float c){ return fminf(fminf(a,b),c); }
__device__ __forceinline__ float max3f(float a,float b,float c){ return fmaxf(fmaxf(a,b),c); }

__global__ __launch_bounds__(512, 8)
void simplenet_fused(const float* __restrict__ X,
                     const float* __restrict__ w0, const float* __restrict__ b0,
                     const float* __restrict__ w1, const float* __restrict__ w2,
                     const float* __restrict__ w3, const float* __restrict__ w4,
                     const float* __restrict__ w5, const float* __restrict__ w6,
                     float* __restrict__ out)
{
    // One interleaved exchange plane: KNX[r][c] = { pk_f16(h11min,-h11max),
    // pk_f16(gaussH, 0) }. Consumer reads 14 ds_read_b64 (8B lane stride)
    // instead of 24 b32. RAW holds raw cols for the trio. Single barrier.
    __shared__ uint2 KNX[PROWS*GST];   // 21504 B
    __shared__ float RAW[35*RST];      // 10080 B

    const int tid = threadIdx.x;
    const int xo = tid & 63, ty = tid >> 6, y0 = ty*4;
    const int bx = blockIdx.x, by = blockIdx.y, bz = blockIdx.z;
    const int tx0 = bx*TW, ty0 = by*TH;
    const bool xe = (bx==0)||(bx==IMG/TW-1);
    const bool ye = (by==0)||(by==IMG/TH-1);
    const float* Xb = X + (size_t)bz*(IMG*IMG);
    const float qn = __builtin_nanf("");

    const float W0c0=w0[0], W0c1=w0[1], B0=b0[0], B1=b0[1];
    const float W1c0=w1[0], W1c1=w1[1], W2c0=w2[0], W2c1=w2[1];
    const float W3c0=w3[0], W3c1=w3[1], W4c0=w4[0], W4c1=w4[1];
    const float W5c0=w5[0], W5c1=w5[1], W6c0=w6[0], W6c1=w6[1];

    const float G0=0.10628875f, G1=0.14032194f, G2=0.16577342f, G3=0.17523179f;

    auto load_task = [&](int t, float* x) -> bool {   // true = fully-OOB row
        const int r = t >> 4, g = t & 15;
        const int gy  = ty0 - 5 + r;
        const int gx0 = tx0 - 8 + 4*g;
        if ((unsigned)gy >= IMG) return true;
        const bool xs = (unsigned)gx0 > (unsigned)(IMG-20);
        if (!xs) {
#pragma unroll
            for (int j=0;j<5;++j) {
                const float4 q = *(const float4*)(Xb + gy*IMG + gx0 + 4*j);
                x[4*j]=q.x; x[4*j+1]=q.y; x[4*j+2]=q.z; x[4*j+3]=q.w;
            }
        } else {
            const float* row = Xb + gy*IMG;
#pragma unroll
            for (int i=0;i<20;++i) {
                const int gx = gx0 + i;
                const float v = row[min(max(gx,0),IMG-1)];
                x[i] = ((unsigned)gx < IMG) ? v : qn;
            }
        }
        return false;
    };
    auto compute_task = [&](int t, const float* x, bool oob) {
        const int r = t >> 4, g = t & 15;
        const int wb = r*GST + 4*g;                // uint2 index, 16B-aligned
        const bool rawrow = (r >= 4 && r <= 38);
        if (oob) {
            const uint4 s0 = make_uint4(0x7BFF7BFFu, 0u, 0x7BFF7BFFu, 0u);
            *(uint4*)&KNX[wb]   = s0;
            *(uint4*)&KNX[wb+2] = s0;
            if (rawrow) {
                *(float4*)&RAW[(r-4)*RST + 4*g + 4] = make_float4(qn,qn,qn,qn);
                if (g==0)  RAW[(r-4)*RST + 3]  = qn;
                if (g==15) RAW[(r-4)*RST + 68] = qn;
            }
            return;
        }
        if (rawrow) {
            *(float4*)&RAW[(r-4)*RST + 4*g + 4] = make_float4(x[8],x[9],x[10],x[11]);
            if (g==0)  RAW[(r-4)*RST + 3]  = x[7];
            if (g==15) RAW[(r-4)*RST + 68] = x[12];
        }
        float mn[12], mx[12];
#pragma unroll
        for (int i=0;i<12;++i) {
            mn[i] = min3f(x[i+3],x[i+4],x[i+5]);
            mx[i] = max3f(x[i+3],x[i+4],x[i+5]);
        }
        unsigned hw[4];
#pragma unroll
        for (int k=0;k<4;++k) {                    // 11-window = m3 at offsets 0,3,6,8
            const float hn = fminf(fminf(mn[k],mn[k+3]), fminf(mn[k+6],mn[k+8]));
            const float hx = fmaxf(fmaxf(mx[k],mx[k+3]), fmaxf(mx[k+6],mx[k+8]));
            UH c; c.h = __builtin_amdgcn_cvt_pkrtz(hn, -hx);
            hw[k] = c.u;
        }
        unsigned gw[4] = {0u,0u,0u,0u};
        if (r >= 2 && r < 40) {                    // gaussH (f16) only where v-window uses it
            const bool xs = (unsigned)(tx0 - 8 + 4*g) > (unsigned)(IMG-20);
            float zz[10];
#pragma unroll
            for (int j=0;j<10;++j) zz[j] = xs ? nan0(x[5+j]) : x[5+j];
#pragma unroll
            for (int k=0;k<4;++k) {
                const float gh = G0*(zz[k]+zz[k+6]) + G1*(zz[k+1]+zz[k+5])
                               + G2*(zz[k+2]+zz[k+4]) + G3*zz[k+3];
                UH c; c.h = __builtin_amdgcn_cvt_pkrtz(gh, 0.f);
                gw[k] = c.u;
            }
        }
        *(uint4*)&KNX[wb]   = make_uint4(hw[0],gw[0],hw[1],gw[1]);
        *(uint4*)&KNX[wb+2] = make_uint4(hw[2],gw[2],hw[3],gw[3]);
    };

    // ---- producers: prefetch BOTH tasks' loads, then compute both ----
    float x0[20], x1[20];
    const bool has1 = tid < (PROWS*16 - 512);   // 160 threads own a 2nd task
    const bool oob0 = load_task(tid, x0);
    bool oob1 = true;
    if (has1) oob1 = load_task(512 + tid, x1);
    compute_task(tid, x0, oob0);
    if (has1) compute_task(512 + tid, x1, oob1);

    __syncthreads();

    float a0[4], a1[4];

    // ---- post-barrier: everything from LDS. Batch loads for ILP. ----
    {
        // trio loads (18 b32, dense)
        float L[6], C[6], R[6];
#pragma unroll
        for (int i=0;i<6;++i) {
            const int base = (y0+i)*RST + xo + 4;
            L[i]=RAW[base-1]; C[i]=RAW[base]; R[i]=RAW[base+1];
        }
        // exchange-plane loads: 14 b64, rows y0..y0+13
        uint2 kq[14];
#pragma unroll
        for (int i=0;i<14;++i) kq[i] = KNX[(y0+i)*GST + xo];

        // ---- trio compute: identity + 3x3 cross + pool3 ----
        float hm[6], hx6[6];
#pragma unroll
        for (int i=0;i<6;++i) { hm[i]=min3f(L[i],C[i],R[i]); hx6[i]=max3f(L[i],C[i],R[i]); }
        float Lz[6], Rz[6];
#pragma unroll
        for (int i=0;i<6;++i) { Lz[i] = xe ? nan0(L[i]) : L[i];
                                Rz[i] = xe ? nan0(R[i]) : R[i]; }
        const float Cz0 = ye ? nan0(C[0]) : C[0];
        const float Cz5 = ye ? nan0(C[5]) : C[5];
        const float up[4]={Cz0,C[1],C[2],C[3]};
        const float dn[4]={C[2],C[3],C[4],Cz5};
#pragma unroll
        for (int p=0;p<4;++p) {
            const float cr = 0.25f*(up[p] + dn[p] + Lz[p+1] + Rz[p+1]);
            a0[p] = B0 + W0c0*C[p+1] + W1c0*cr;
            a1[p] = B1 + W0c1*C[p+1] + W1c1*cr;
            const float mnv = min3f(hm[p],hm[p+1],hm[p+2]);
            const float mxv = max3f(hx6[p],hx6[p+1],hx6[p+2]);
            a0[p] += W3c0*mnv + W5c0*mxv;
            a1[p] += W3c1*mnv + W5c1*mxv;
        }

        // ---- gaussV from f16 gaussH (rows y0+2..y0+11 -> kq[2..11].y) ----
        float wv[10];
#pragma unroll
        for (int i=0;i<10;++i) { UH u; u.u = kq[i+2].y; wv[i] = (float)u.h[0]; }
#pragma unroll
        for (int p=0;p<4;++p) {
            const float s = G0*(wv[p]+wv[p+6]) + G1*(wv[p+1]+wv[p+5])
                          + G2*(wv[p+2]+wv[p+4]) + G3*wv[p+3];
            a0[p] += W2c0*s; a1[p] += W2c1*s;
        }

        // ---- v11 van Herk, both chains per packed op (lo=min, hi=-max) ----
        h2v q[14];
#pragma unroll
        for (int i=0;i<14;++i) { UH u; u.u = kq[i].x; q[i] = u.h; }
        h2v s = q[10];
#pragma unroll
        for (int i=9;i>=4;--i) s = __builtin_elementwise_min(s, q[i]);
        const h2v S3 = __builtin_elementwise_min(s,  q[3]);
        const h2v S2 = __builtin_elementwise_min(S3, q[2]);
        const h2v S1 = __builtin_elementwise_min(S2, q[1]);
        const h2v S0 = __builtin_elementwise_min(S1, q[0]);
        const h2v p1 = q[11];
        const h2v p2 = __builtin_elementwise_min(p1, q[12]);
        const h2v p3 = __builtin_elementwise_min(p2, q[13]);
        const h2v o0 = S0;
        const h2v o1 = __builtin_elementwise_min(S1, p1);
        const h2v o2 = __builtin_elementwise_min(S2, p2);
        const h2v o3 = __builtin_elementwise_min(S3, p3);
        const float on[4] = {(float)o0[0], (float)o1[0], (float)o2[0], (float)o3[0]};
        const float ox[4] = {-(float)o0[1], -(float)o1[1], -(float)o2[1], -(float)o3[1]};
#pragma unroll
        for (int p=0;p<4;++p) {
            a0[p] += W4c0*on[p] + W6c0*ox[p];
            a1[p] += W4c1*on[p] + W6c1*ox[p];
        }
    }

    float* o0p = out + ((size_t)bz*2 + 0)*(IMG*IMG) + (size_t)(ty0+y0)*IMG + tx0 + xo;
    float* o1p = o0p + (IMG*IMG);
#pragma unroll
    for (int p=0;p<4;++p) {
        o0p[(size_t)p*IMG] = a0[p];
        o1p[(size_t)p*IMG] = a1[p];
    }
}

extern "C" void kernel_launch(void* const* d_in, const int* in_sizes, int n_in,
                              void* d_out, int out_size, void* d_ws, size_t ws_size,
                              hipStream_t stream) {
    const float* X  = (const float*)d_in[0];
    const float* w0 = (const float*)d_in[1];
    const float* b0 = (const float*)d_in[2];
    const float* w1 = (const float*)d_in[3];
    const float* w2 = (const float*)d_in[4];
    const float* w3 = (const float*)d_in[5];
    const float* w4 = (const float*)d_in[6];
    const float* w5 = (const float*)d_in[7];
    const float* w6 = (const float*)d_in[8];
    float* out = (float*)d_out;

    dim3 grid(IMG/TW, IMG/TH, 32);
    simplenet_fused<<<grid, 512, 0, stream>>>(X, w0, b0, w1, w2, w3, w4, w5, w6, out);
}